// Round 1
// baseline (222.268 us; speedup 1.0000x reference)
//
#include <hip/hip_runtime.h>

#define SEQ 23
#define DIM 10
#define DP  12   // padded LDS row stride (48 B -> 16B-aligned rows)
#define BPB 11   // batches per block (11*23 = 253 active threads of 256)
#define NTHR 256

__global__ __launch_bounds__(NTHR) void attn_fused_kernel(
    const float* __restrict__ x,    // [B][23][10]
    const float* __restrict__ Wk,   // [10][10]  (row = out k, col = in d)
    const float* __restrict__ Wq,   // [10][10]
    const float* __restrict__ Wv,   // [10][10]
    float* __restrict__ out,        // [B][230]
    int B)
{
    __shared__ __align__(16) float sM[DIM][DP];    // scale * Wq^T * Wk
    __shared__ __align__(16) float sWv[DIM][DP];   // Wv as given [e][d]
    __shared__ __align__(16) float ub[BPB][SEQ][DP];  // u_j = M x_j
    __shared__ __align__(16) float vb[BPB][SEQ][DP];  // v_j = Wv x_j

    const int tid = threadIdx.x;

    // ---- per-block weight setup (tiny; inputs L2-resident) ----
    if (tid < 100) {
        const int a = tid / 10, b2 = tid % 10;
        float acc = 0.f;
        #pragma unroll
        for (int k = 0; k < 10; ++k)
            acc += Wq[k * 10 + a] * Wk[k * 10 + b2];
        sM[a][b2] = acc * 0.31622776601683794f;   // 1/sqrt(10)
    } else if (tid < 200) {
        const int t = tid - 100;
        sWv[t / 10][t % 10] = Wv[t];
    }
    __syncthreads();

    const int bl = tid / SEQ;          // local batch index 0..10
    const int i  = tid - bl * SEQ;     // row 0..22
    const long b = (long)blockIdx.x * BPB + bl;
    const bool active = (tid < BPB * SEQ) && (b < (long)B);

    float xr[DIM];
    if (active) {
        const float* xp = x + (b * SEQ + i) * DIM;
        #pragma unroll
        for (int d = 0; d < DIM; d += 2) {
            float2 t = *reinterpret_cast<const float2*>(xp + d);
            xr[d] = t.x; xr[d + 1] = t.y;
        }
        // u_i = M x_i ; v_i = Wv x_i  -> LDS
        #pragma unroll
        for (int a = 0; a < DIM; ++a) {
            float au = 0.f, av = 0.f;
            #pragma unroll
            for (int d = 0; d < DIM; ++d) {
                au += sM[a][d]  * xr[d];
                av += sWv[a][d] * xr[d];
            }
            ub[bl][i][a] = au;
            vb[bl][i][a] = av;
        }
    }
    __syncthreads();
    if (!active) return;   // no further barriers below

    // ---- logits row i : s[j] = x_i . u_j  (scale folded into M) ----
    float s[SEQ];
    #pragma unroll
    for (int j = 0; j < SEQ; ++j) {
        float acc = 0.f;
        #pragma unroll
        for (int a = 0; a < DIM; ++a)
            acc += xr[a] * ub[bl][j][a];
        s[j] = acc;
    }

    // ---- softmax over j, fully in registers ----
    float m = s[0];
    #pragma unroll
    for (int j = 1; j < SEQ; ++j) m = fmaxf(m, s[j]);
    float sum = 0.f;
    #pragma unroll
    for (int j = 0; j < SEQ; ++j) { s[j] = __expf(s[j] - m); sum += s[j]; }
    const float inv = __frcp_rn(sum);

    // ---- context row i : c = sum_j p_j * v_j ----
    float c[DIM];
    #pragma unroll
    for (int e = 0; e < DIM; ++e) c[e] = 0.f;
    #pragma unroll
    for (int j = 0; j < SEQ; ++j) {
        const float p = s[j] * inv;
        #pragma unroll
        for (int e = 0; e < DIM; ++e)
            c[e] += p * vb[bl][j][e];
    }

    // ---- residual add + store ----
    float* op = out + b * (SEQ * DIM) + i * DIM;
    #pragma unroll
    for (int d = 0; d < DIM; d += 2) {
        float2 t;
        t.x = xr[d]     + c[d];
        t.y = xr[d + 1] + c[d + 1];
        *reinterpret_cast<float2*>(op + d) = t;
    }
}

extern "C" void kernel_launch(void* const* d_in, const int* in_sizes, int n_in,
                              void* d_out, int out_size, void* d_ws, size_t ws_size,
                              hipStream_t stream) {
    const float* x  = (const float*)d_in[0];
    const float* Wk = (const float*)d_in[1];
    const float* Wq = (const float*)d_in[2];
    const float* Wv = (const float*)d_in[3];
    float* out = (float*)d_out;

    const int B = in_sizes[0] / (SEQ * DIM);
    const int blocks = (B + BPB - 1) / BPB;
    hipLaunchKernelGGL(attn_fused_kernel, dim3(blocks), dim3(NTHR), 0, stream,
                       x, Wk, Wq, Wv, out, B);
}

// Round 2
// 132.880 us; speedup vs baseline: 1.6727x; 1.6727x over previous
//
#include <hip/hip_runtime.h>
#include <hip/hip_fp16.h>

#define SEQ 23
#define DIM 10
#define BPB 11   // batches per block (11*23 = 253 active of 256)
#define NTHR 256

typedef _Float16 hf2 __attribute__((ext_vector_type(2)));

static __device__ __forceinline__ float fdot2(hf2 a, hf2 b, float c) {
#if __has_builtin(__builtin_amdgcn_fdot2)
    return __builtin_amdgcn_fdot2(a, b, c, false);
#else
    return c + (float)a[0] * (float)b[0] + (float)a[1] * (float)b[1];
#endif
}

static __device__ __forceinline__ unsigned pack2(float a, float b) {
    __half2 h = __floats2half2_rn(a, b);   // v_cvt_pkrtz_f16_f32: a->lo, b->hi
    return __builtin_bit_cast(unsigned, h);
}
static __device__ __forceinline__ hf2 u2h(unsigned u) {
    return __builtin_bit_cast(hf2, u);
}
static __device__ __forceinline__ __half2 u2hh(unsigned u) {
    return __builtin_bit_cast(__half2, u);
}

// ---- prep: M = scale * Wq^T * Wk and Wv, packed to f16 pairs in d_ws ----
// layout: ws[a*5+p]    = half2(M[a][2p],  M[a][2p+1])    a,p: a<10, p<5
//         ws[50+e*5+p] = half2(Wv[e][2p], Wv[e][2p+1])
__global__ void attn_prep_kernel(const float* __restrict__ Wk,
                                 const float* __restrict__ Wq,
                                 const float* __restrict__ Wv,
                                 unsigned* __restrict__ ws) {
    const int t = threadIdx.x;
    if (t < 50) {
        const int a = t / 5, p = t % 5;
        float m0 = 0.f, m1 = 0.f;
        #pragma unroll
        for (int k = 0; k < 10; ++k) {
            m0 += Wq[k * 10 + a] * Wk[k * 10 + 2 * p];
            m1 += Wq[k * 10 + a] * Wk[k * 10 + 2 * p + 1];
        }
        const float sc = 0.31622776601683794f;  // 1/sqrt(10)
        ws[t] = pack2(m0 * sc, m1 * sc);
    } else if (t < 100) {
        const int e = (t - 50) / 5, p = (t - 50) % 5;
        ws[t] = pack2(Wv[e * 10 + 2 * p], Wv[e * 10 + 2 * p + 1]);
    }
}

__global__ __launch_bounds__(NTHR) void attn_main_kernel(
    const float* __restrict__ x,      // [B][23][10] f32
    const unsigned* __restrict__ wsu, // packed weights (read-only -> s_load)
    float* __restrict__ out,          // [B][230] f32
    int B)
{
    // rows padded to 8 dwords (32 B) => b128+b32 per row read
    __shared__ __align__(16) unsigned ub2[BPB][SEQ][8];
    __shared__ __align__(16) unsigned vb2[BPB][SEQ][8];

    const int tid = threadIdx.x;
    const int bl  = tid / SEQ;
    const int i   = tid - bl * SEQ;
    const long b  = (long)blockIdx.x * BPB + bl;
    const bool act = (tid < BPB * SEQ) && (b < (long)B);

    float xr[DIM];
    hf2   xp[5];

    if (act) {
        const float* xpr = x + (b * SEQ + i) * DIM;
        #pragma unroll
        for (int p = 0; p < 5; ++p) {
            float2 t = *reinterpret_cast<const float2*>(xpr + 2 * p);
            xr[2 * p] = t.x; xr[2 * p + 1] = t.y;
            xp[p] = u2h(pack2(t.x, t.y));
        }
        // u = M x ; v = Wv x   (weights via scalar loads, dot2 math)
        unsigned urow[5], vrow[5];
        #pragma unroll
        for (int q = 0; q < 5; ++q) {
            float u0 = 0.f, u1 = 0.f, v0 = 0.f, v1 = 0.f;
            #pragma unroll
            for (int p = 0; p < 5; ++p) {
                u0 = fdot2(xp[p], u2h(wsu[(2 * q)     * 5 + p]), u0);
                u1 = fdot2(xp[p], u2h(wsu[(2 * q + 1) * 5 + p]), u1);
                v0 = fdot2(xp[p], u2h(wsu[50 + (2 * q)     * 5 + p]), v0);
                v1 = fdot2(xp[p], u2h(wsu[50 + (2 * q + 1) * 5 + p]), v1);
            }
            urow[q] = pack2(u0, u1);
            vrow[q] = pack2(v0, v1);
        }
        *reinterpret_cast<uint4*>(&ub2[bl][i][0]) =
            make_uint4(urow[0], urow[1], urow[2], urow[3]);
        ub2[bl][i][4] = urow[4];
        *reinterpret_cast<uint4*>(&vb2[bl][i][0]) =
            make_uint4(vrow[0], vrow[1], vrow[2], vrow[3]);
        vb2[bl][i][4] = vrow[4];
    }
    __syncthreads();
    if (!act) return;

    // ---- logits: s[j] = x_i . u_j  (f16 dot2, f32 accum) ----
    float s[SEQ];
    #pragma unroll
    for (int j = 0; j < SEQ; ++j) {
        const unsigned* r = &ub2[bl][j][0];
        uint4 r03 = *reinterpret_cast<const uint4*>(r);
        unsigned r4 = r[4];
        float acc = 0.f;
        acc = fdot2(xp[0], u2h(r03.x), acc);
        acc = fdot2(xp[1], u2h(r03.y), acc);
        acc = fdot2(xp[2], u2h(r03.z), acc);
        acc = fdot2(xp[3], u2h(r03.w), acc);
        acc = fdot2(xp[4], u2h(r4),    acc);
        s[j] = acc;
    }

    // ---- softmax (f32, in registers) ----
    float m = s[0];
    #pragma unroll
    for (int j = 1; j < SEQ; ++j) m = fmaxf(m, s[j]);
    float sum = 0.f;
    #pragma unroll
    for (int j = 0; j < SEQ; ++j) { s[j] = __expf(s[j] - m); sum += s[j]; }
    const float inv = __builtin_amdgcn_rcpf(sum);

    // ---- context: c = sum_j p_j v_j  (packed f16 FMA) ----
    __half2 c2[5];
    #pragma unroll
    for (int q = 0; q < 5; ++q) c2[q] = __float2half2_rn(0.f);
    #pragma unroll
    for (int j = 0; j < SEQ; ++j) {
        const unsigned* r = &vb2[bl][j][0];
        uint4 r03 = *reinterpret_cast<const uint4*>(r);
        unsigned r4 = r[4];
        __half2 ph = __float2half2_rn(s[j] * inv);
        c2[0] = __hfma2(ph, u2hh(r03.x), c2[0]);
        c2[1] = __hfma2(ph, u2hh(r03.y), c2[1]);
        c2[2] = __hfma2(ph, u2hh(r03.z), c2[2]);
        c2[3] = __hfma2(ph, u2hh(r03.w), c2[3]);
        c2[4] = __hfma2(ph, u2hh(r4),    c2[4]);
    }

    // ---- residual + store ----
    float* op = out + b * (SEQ * DIM) + i * DIM;
    #pragma unroll
    for (int q = 0; q < 5; ++q) {
        float2 cf = __half22float2(c2[q]);
        float2 t;
        t.x = xr[2 * q]     + cf.x;
        t.y = xr[2 * q + 1] + cf.y;
        *reinterpret_cast<float2*>(op + 2 * q) = t;
    }
}

extern "C" void kernel_launch(void* const* d_in, const int* in_sizes, int n_in,
                              void* d_out, int out_size, void* d_ws, size_t ws_size,
                              hipStream_t stream) {
    const float* x  = (const float*)d_in[0];
    const float* Wk = (const float*)d_in[1];
    const float* Wq = (const float*)d_in[2];
    const float* Wv = (const float*)d_in[3];
    float* out = (float*)d_out;
    unsigned* ws = (unsigned*)d_ws;

    const int B = in_sizes[0] / (SEQ * DIM);
    hipLaunchKernelGGL(attn_prep_kernel, dim3(1), dim3(128), 0, stream,
                       Wk, Wq, Wv, ws);
    const int blocks = (B + BPB - 1) / BPB;
    hipLaunchKernelGGL(attn_main_kernel, dim3(blocks), dim3(NTHR), 0, stream,
                       x, ws, out, B);
}

// Round 3
// 124.683 us; speedup vs baseline: 1.7827x; 1.0657x over previous
//
#include <hip/hip_runtime.h>
#include <hip/hip_fp16.h>

#define SEQ 23
#define DIM 10
#define BPB 11   // batches per block (11*23 = 253 active of 256)
#define NTHR 256

typedef _Float16 hf2 __attribute__((ext_vector_type(2)));

static __device__ __forceinline__ float fdot2(hf2 a, hf2 b, float c) {
#if __has_builtin(__builtin_amdgcn_fdot2)
    return __builtin_amdgcn_fdot2(a, b, c, false);
#else
    return c + (float)a[0] * (float)b[0] + (float)a[1] * (float)b[1];
#endif
}
static __device__ __forceinline__ float fastexp2(float x) {
#if __has_builtin(__builtin_amdgcn_exp2f)
    return __builtin_amdgcn_exp2f(x);
#else
    return exp2f(x);
#endif
}
static __device__ __forceinline__ unsigned pack2(float a, float b) {
    __half2 h = __floats2half2_rn(a, b);   // v_cvt_pkrtz_f16_f32
    return __builtin_bit_cast(unsigned, h);
}
static __device__ __forceinline__ hf2 u2h(unsigned u) {
    return __builtin_bit_cast(hf2, u);
}
static __device__ __forceinline__ __half2 u2hh(unsigned u) {
    return __builtin_bit_cast(__half2, u);
}

// ---- prep: M = (scale*log2e) * Wq^T * Wk and Wv, packed f16 pairs in d_ws ----
// ws[a*5+p]    = half2(M[a][2p],  M[a][2p+1])
// ws[50+e*5+p] = half2(Wv[e][2p], Wv[e][2p+1])
__global__ void attn_prep_kernel(const float* __restrict__ Wk,
                                 const float* __restrict__ Wq,
                                 const float* __restrict__ Wv,
                                 unsigned* __restrict__ ws) {
    const int t = threadIdx.x;
    if (t < 50) {
        const int a = t / 5, p = t % 5;
        float m0 = 0.f, m1 = 0.f;
        #pragma unroll
        for (int k = 0; k < 10; ++k) {
            m0 += Wq[k * 10 + a] * Wk[k * 10 + 2 * p];
            m1 += Wq[k * 10 + a] * Wk[k * 10 + 2 * p + 1];
        }
        // 1/sqrt(10) * log2(e): logits in log2 units -> raw v_exp_f32
        const float sc = 0.31622776601683794f * 1.44269504088896340f;
        ws[t] = pack2(m0 * sc, m1 * sc);
    } else if (t < 100) {
        const int e = (t - 50) / 5, p = (t - 50) % 5;
        ws[t] = pack2(Wv[e * 10 + 2 * p], Wv[e * 10 + 2 * p + 1]);
    }
}

__global__ __launch_bounds__(NTHR, 8) void attn_main_kernel(
    const float* __restrict__ x,      // [B][23][10] f32
    const unsigned* __restrict__ wsu, // packed weights (uniform -> s_load)
    float* __restrict__ out,          // [B][230] f32
    int B)
{
    __shared__ __align__(16) unsigned ub2[BPB][SEQ][8];  // u_j f16 pairs, 32B rows
    __shared__ __align__(16) unsigned vb2[BPB][SEQ][8];  // v_j f16 pairs

    const int tid = threadIdx.x;
    const int bl  = tid / SEQ;
    const int i   = tid - bl * SEQ;
    const long b  = (long)blockIdx.x * BPB + bl;
    const bool act = (tid < BPB * SEQ) && (b < (long)B);

    float xr[DIM];
    hf2   xp[5];

    if (act) {
        const float* xpr = x + (b * SEQ + i) * DIM;
        #pragma unroll
        for (int p = 0; p < 5; ++p) {
            float2 t = *reinterpret_cast<const float2*>(xpr + 2 * p);
            xr[2 * p] = t.x; xr[2 * p + 1] = t.y;
            xp[p] = u2h(pack2(t.x, t.y));
        }
        unsigned urow[5], vrow[5];
        #pragma unroll
        for (int q = 0; q < 5; ++q) {
            float u0 = 0.f, u1 = 0.f, v0 = 0.f, v1 = 0.f;
            #pragma unroll
            for (int p = 0; p < 5; ++p) {
                u0 = fdot2(xp[p], u2h(wsu[(2 * q)     * 5 + p]), u0);
                u1 = fdot2(xp[p], u2h(wsu[(2 * q + 1) * 5 + p]), u1);
                v0 = fdot2(xp[p], u2h(wsu[50 + (2 * q)     * 5 + p]), v0);
                v1 = fdot2(xp[p], u2h(wsu[50 + (2 * q + 1) * 5 + p]), v1);
            }
            urow[q] = pack2(u0, u1);
            vrow[q] = pack2(v0, v1);
        }
        *reinterpret_cast<uint4*>(&ub2[bl][i][0]) =
            make_uint4(urow[0], urow[1], urow[2], urow[3]);
        ub2[bl][i][4] = urow[4];
        *reinterpret_cast<uint4*>(&vb2[bl][i][0]) =
            make_uint4(vrow[0], vrow[1], vrow[2], vrow[3]);
        vb2[bl][i][4] = vrow[4];
    }
    __syncthreads();
    if (!act) return;

#define FOR23(X) X(0) X(1) X(2) X(3) X(4) X(5) X(6) X(7) X(8) X(9) X(10) X(11) \
                 X(12) X(13) X(14) X(15) X(16) X(17) X(18) X(19) X(20) X(21) X(22)

    // ---- logits (log2 units): s_J = x_i . u_J, explicit scalars ----
#define DECLS(J) float s##J;
    FOR23(DECLS)
#define LOGIT(J) { const unsigned* r = &ub2[bl][J][0]; \
    uint4 q4 = *reinterpret_cast<const uint4*>(r); unsigned q1 = r[4]; \
    float a = fdot2(xp[0], u2h(q4.x), 0.f); \
    a = fdot2(xp[1], u2h(q4.y), a); \
    a = fdot2(xp[2], u2h(q4.z), a); \
    a = fdot2(xp[3], u2h(q4.w), a); \
    a = fdot2(xp[4], u2h(q1),   a); \
    s##J = a; }
    FOR23(LOGIT)

    // ---- max via 3-way tree (v_max3_f32 friendly) ----
#define F3(a, b, c) fmaxf(fmaxf((a), (b)), (c))
    const float t0 = F3(s0, s1, s2),   t1 = F3(s3, s4, s5);
    const float t2 = F3(s6, s7, s8),   t3 = F3(s9, s10, s11);
    const float t4 = F3(s12, s13, s14), t5 = F3(s15, s16, s17);
    const float t6 = F3(s18, s19, s20), t7 = fmaxf(s21, s22);
    const float u0m = F3(t0, t1, t2), u1m = F3(t3, t4, t5), u2m = fmaxf(t6, t7);
    const float m = F3(u0m, u1m, u2m);

    // ---- PV with unnormalized p = exp2(s - m)  (f16-safe: p<=1) ----
    __half2 c2[5];
    #pragma unroll
    for (int q = 0; q < 5; ++q) c2[q] = __float2half2_rn(0.f);
    float sm[4] = {0.f, 0.f, 0.f, 0.f};

#define PV(J) { const float p = fastexp2(s##J - m); sm[(J) & 3] += p; \
    const __half2 ph = __float2half2_rn(p); \
    const unsigned* r = &vb2[bl][J][0]; \
    uint4 q4 = *reinterpret_cast<const uint4*>(r); unsigned q1 = r[4]; \
    c2[0] = __hfma2(ph, u2hh(q4.x), c2[0]); \
    c2[1] = __hfma2(ph, u2hh(q4.y), c2[1]); \
    c2[2] = __hfma2(ph, u2hh(q4.z), c2[2]); \
    c2[3] = __hfma2(ph, u2hh(q4.w), c2[3]); \
    c2[4] = __hfma2(ph, u2hh(q1),   c2[4]); }
    FOR23(PV)

    const float inv = __builtin_amdgcn_rcpf((sm[0] + sm[1]) + (sm[2] + sm[3]));

    // ---- residual + normalize fused: out = x + c * inv ----
    float* op = out + b * (SEQ * DIM) + i * DIM;
    #pragma unroll
    for (int q = 0; q < 5; ++q) {
        float2 cf = __half22float2(c2[q]);
        float2 t;
        t.x = fmaf(cf.x, inv, xr[2 * q]);
        t.y = fmaf(cf.y, inv, xr[2 * q + 1]);
        *reinterpret_cast<float2*>(op + 2 * q) = t;
    }
}

extern "C" void kernel_launch(void* const* d_in, const int* in_sizes, int n_in,
                              void* d_out, int out_size, void* d_ws, size_t ws_size,
                              hipStream_t stream) {
    const float* x  = (const float*)d_in[0];
    const float* Wk = (const float*)d_in[1];
    const float* Wq = (const float*)d_in[2];
    const float* Wv = (const float*)d_in[3];
    float* out = (float*)d_out;
    unsigned* ws = (unsigned*)d_ws;

    const int B = in_sizes[0] / (SEQ * DIM);
    hipLaunchKernelGGL(attn_prep_kernel, dim3(1), dim3(128), 0, stream,
                       Wk, Wq, Wv, ws);
    const int blocks = (B + BPB - 1) / BPB;
    hipLaunchKernelGGL(attn_main_kernel, dim3(blocks), dim3(NTHR), 0, stream,
                       x, ws, out, B);
}